// Round 17
// baseline (121.577 us; speedup 1.0000x reference)
//
#include <hip/hip_runtime.h>
#include <hip/hip_bf16.h>
#include <math.h>

#define Bn 16
#define Tn 2048
#define Wn 10
constexpr float PI_F = 3.14159265358979323846f;

typedef __bf16 bf16x8 __attribute__((ext_vector_type(8)));
typedef __bf16 bf16x4 __attribute__((ext_vector_type(4)));
typedef float  f32x4  __attribute__((ext_vector_type(4)));

// ---- output offsets (floats) ----
constexpr size_t O_EMB   = 0;
constexpr size_t O_PSPEC = (size_t)Bn*Tn*256;            // 8388608
constexpr size_t O_PPAR  = O_PSPEC + (size_t)Bn*Tn*20;   // 9043968
constexpr size_t O_TSPEC = O_PPAR + 2*Bn;                // 9044000
constexpr size_t O_TPAR  = O_TSPEC + (size_t)Bn*Tn*20;   // 9699360

// ---- workspace BYTE offsets ----
constexpr size_t OB_WB1  = 0;
constexpr size_t OB_WB2  = OB_WB1 + 393216;
constexpr size_t OB_LWB  = OB_WB2 + 393216;               // 16KB lw B-frag image
constexpr size_t OB_P2   = OB_LWB + 16384;                // B*T*2 f32
constexpr size_t OB_SCR  = OB_P2 + 262144;                // 16MB scratch union:
constexpr size_t OB_X    = OB_SCR;
constexpr size_t OB_Y1   = OB_SCR + 1441792;
constexpr size_t OB_Y    = OB_SCR;

__device__ __forceinline__ void gld_lds16(const void* g, void* l){
  __builtin_amdgcn_global_load_lds(
      (const __attribute__((address_space(1))) unsigned int*)g,
      (__attribute__((address_space(3))) unsigned int*)l, 16, 0, 0);
}

// ---- weight prep (conv images + lw image, single launch) ----
__global__ void k_prep_w(const float* __restrict__ w1, const float* __restrict__ w2,
                         const float* __restrict__ lw,
                         char* __restrict__ wb1, char* __restrict__ wb2,
                         char* __restrict__ lwB){
  int idx = blockIdx.x*256 + threadIdx.x;     // 401408 = 2*196608 + 8192
  if (idx >= 393216){
    int r2 = idx - 393216;
    int col = r2 >> 8, k = r2 & 255;
    float v = (col < 22) ? lw[col*256 + k] : 0.f;
    size_t off = (size_t)col*512 + ((((k>>3)*16)) ^ ((col&7)<<4)) + ((k&7)<<1);
    *(__bf16*)(lwB + off) = (__bf16)v;
    return;
  }
  const float* w = w1; char* wb = wb1;
  if (idx >= 196608){ idx -= 196608; w = w2; wb = wb2; }
  int ns   = idx / 49152;
  int rem  = idx - ns*49152;
  int s    = rem >> 11;
  int rem2 = rem & 2047;
  int o_l  = rem2 >> 5;
  int kk   = rem2 & 31;
  int o  = ns*64 + o_l;
  int k3 = s >> 3;
  int i  = (s & 7)*32 + kk;
  float v = w[((size_t)o*256 + i)*3 + k3];
  size_t off = (size_t)ns*98304 + (size_t)s*4096 + o_l*64
             + ((((kk>>3)<<4)) ^ ((o_l&6)<<3)) + ((kk&7)<<1);
  *(__bf16*)(wb + off) = (__bf16)v;
}

// ======== forward DFT with fused per-batch stats ========
__global__ void k_fwd_dft(const float* __restrict__ target, const int* __restrict__ mel,
                          float* __restrict__ X, float* __restrict__ tpar){
  __shared__ float cbuf[Tn];
  __shared__ float2 tw[Tn];
  __shared__ float red[256];
  __shared__ float msh[2];
  int b = blockIdx.x >> 6, kc = blockIdx.x & 63, tid = threadIdx.x;
  int len = mel[b];
  float lenf = (float)len;
  float s = 0.f;
  for (int n=tid; n<Tn; n+=256){ float v = target[(size_t)b*Tn+n]; cbuf[n] = v; s += v; }
  red[tid]=s; __syncthreads();
  for (int off=128; off; off>>=1){ if(tid<off) red[tid]+=red[tid+off]; __syncthreads(); }
  if (tid==0) msh[0] = red[0]/lenf;
  __syncthreads();
  float mean = msh[0];
  float s2 = 0.f;
  for (int n=tid; n<Tn; n+=256){ float d = (n<len)?(cbuf[n]-mean):0.f; s2 += d*d; }
  red[tid]=s2; __syncthreads();
  for (int off=128; off; off>>=1){ if(tid<off) red[tid]+=red[tid+off]; __syncthreads(); }
  if (tid==0) msh[1] = sqrtf(red[0]/(lenf-1.f));
  __syncthreads();
  float stdv = msh[1];
  if (kc==0 && tid==0){ tpar[2*b] = mean; tpar[2*b+1] = stdv; }
  float istd = 1.f/stdv;
  for (int n=tid; n<Tn; n+=256){
    float sn, cs;
    sincosf((2.f*PI_F/Tn)*n, &sn, &cs);
    tw[n] = make_float2(cs, sn);
    cbuf[n] = (n<len) ? (cbuf[n]-mean)*istd : 0.f;
  }
  __syncthreads();
  int k  = (kc<<4) | (tid>>4);
  int tl = tid & 15;
  float xr=0.f, xi=0.f;
  for (int t=tl; t<Tn; t+=16){
    int n = (k*t) & (Tn-1);
    float2 w = tw[n];
    float cv = cbuf[t];
    xr += cv*w.x;
    xi -= cv*w.y;
  }
  #pragma unroll
  for (int m=1; m<16; m<<=1){ xr += __shfl_xor(xr,m); xi += __shfl_xor(xi,m); }
  if (tl==0){ X[2*(b*1024+k)] = xr; X[2*(b*1024+k)+1] = xi; }
}

// ======== inverse DFT stage 1, fused psi-multiply ========
__global__ __launch_bounds__(256) void k_idft1(const float* __restrict__ X,
                                               float* __restrict__ Y1){
  __shared__ float zc[640];
  __shared__ float2 tw64[64];
  int c = blockIdx.x, b = blockIdx.y, tid = threadIdx.x;
  if (tid < 64){
    float sn, cs;
    sincosf((2.f*PI_F/64.f)*tid, &sn, &cs);
    tw64[tid] = make_float2(cs, sn);
  }
  const float pref = 0.7511255444649425f;  // pi^-0.25
  for (int i = tid; i < 640; i += 256){
    int a = i / 20, j = i - a*20;
    int k = a*32 + c;
    int sidx = j >> 1;
    float omega = (2.f*PI_F/Tn)*k;
    float sc = expf(0.4f*(float)sidx);
    float arg = sc*omega - 6.0f;
    float psi = (k>0) ? pref*sqrtf(2.f*PI_F*sc)*expf(-0.5f*arg*arg)*(1.f/Tn) : 0.f;
    float xv = X[2*((size_t)b*1024 + k) + (j&1)];
    zc[i] = xv * psi;
  }
  __syncthreads();
  int u = tid & 63, g = tid >> 6;
  float* dst = Y1 + (((size_t)b*32 + c)*64 + u)*20;
  for (int s = g; s < 10; s += 4){
    float yr = 0.f, yi = 0.f;
    #pragma unroll
    for (int a = 0; a < 32; a++){
      float2 w = tw64[(a*u) & 63];
      float zr = zc[a*20 + 2*s], zi = zc[a*20 + 2*s + 1];
      yr += zr*w.x - zi*w.y;
      yi += zr*w.y + zi*w.x;
    }
    dst[2*s]   = yr;
    dst[2*s+1] = yi;
  }
}

__global__ __launch_bounds__(256) void k_idft2(const float* __restrict__ Y1,
                                               const int* __restrict__ mel,
                                               float* __restrict__ tspec){
  __shared__ float2 tw[Tn];
  __shared__ float ys[640];
  int u = blockIdx.x, b = blockIdx.y, tid = threadIdx.x;
  for (int n = tid; n < Tn; n += 256){
    float sn, cs;
    sincosf((2.f*PI_F/Tn)*n, &sn, &cs);
    tw[n] = make_float2(cs, sn);
  }
  for (int i = tid; i < 640; i += 256){
    int c = i / 20, j = i - c*20;
    ys[i] = Y1[(((size_t)b*32 + c)*64 + u)*20 + j];
  }
  __syncthreads();
  int len = mel[b];
  int j = tid >> 3, l8 = tid & 7;
  int t = u + (j << 6);
  if (l8 < 5){
    #pragma unroll
    for (int sp = 0; sp < 2; sp++){
      int s = l8 + sp*5;
      float wr = 0.f, wi = 0.f;
      #pragma unroll
      for (int c = 0; c < 32; c++){
        float2 w = tw[(c*t) & (Tn-1)];
        float yr = ys[c*20 + 2*s], yi = ys[c*20 + 2*s + 1];
        wr += yr*w.x - yi*w.y;
        wi += yr*w.y + yi*w.x;
      }
      bool ok = (t < len);
      tspec[((size_t)b*Tn + t)*20 + s]      = ok ? wr : 0.f;
      tspec[((size_t)b*Tn + t)*20 + s + 10] = ok ? wi : 0.f;
    }
  }
}

// ======== conv GEMM v4: reg-B; STAGE2 fuses LN1+relu into staging ========
// Row r of a task is staged by 32 consecutive lanes of ONE wave -> LN via
// 5-level shfl_xor inside the 32-lane group.  Per-thread channel slice is
// j-invariant (sg = tid&31), so g/be load once.
template<int STAGE>
__global__ __launch_bounds__(256) void k_conv_gemm(
    const void* __restrict__ in_v, const char* __restrict__ wBimg,
    const float* __restrict__ cb, const float* __restrict__ lng,
    const float* __restrict__ lnb, __bf16* __restrict__ yb)
{
  __shared__ char smA[34*512];              // 17408 B
  __shared__ char smY[32*128];              // 4096 B
  const int tid = threadIdx.x;
  const int tg = blockIdx.x, ns = blockIdx.y, b = blockIdx.z;
  const int w = tid >> 6, l = tid & 63, lm = l & 15, lk = l >> 4;
  const int o_l = w*16 + lm;
  const int och = ns*64 + o_l;
  const int sg_ch = (tid & 31)*8;           // this thread's channel slice

  float4 va[4], vb4[4]; bf16x8 vv[4];
  float4 ta0, ta1; bf16x8 tv;

  float4 lg0, lg1, lb0, lb1;
  if (STAGE==2){
    lg0 = *(const float4*)(lng + sg_ch);  lg1 = *(const float4*)(lng + sg_ch + 4);
    lb0 = *(const float4*)(lnb + sg_ch);  lb1 = *(const float4*)(lnb + sg_ch + 4);
  }

  auto LOADA = [&](int task){
    int tbase = (tg*8 + task)*32;
    #pragma unroll
    for (int j=0; j<4; j++){
      int gi = tid + j*256;
      int r = gi >> 5, sg = gi & 31;
      int tc = min(max(tbase + r - 1, 0), Tn-1);
      if (STAGE==1){
        const float4* src = (const float4*)((const float*)in_v + ((size_t)b*Tn + tc)*256 + sg*8);
        va[j] = src[0]; vb4[j] = src[1];
      } else {
        vv[j] = *(const bf16x8*)((const __bf16*)in_v + ((size_t)b*Tn + tc)*256 + sg*8);
      }
    }
    if (tid < 64){
      int gi = 1024 + tid;
      int r = gi >> 5, sg = gi & 31;
      int tc = min(max(tbase + r - 1, 0), Tn-1);
      if (STAGE==1){
        const float4* src = (const float4*)((const float*)in_v + ((size_t)b*Tn + tc)*256 + sg*8);
        ta0 = src[0]; ta1 = src[1];
      } else {
        tv = *(const bf16x8*)((const __bf16*)in_v + ((size_t)b*Tn + tc)*256 + sg*8);
      }
    }
  };

  // LN+relu a staged bf16x8 within its 32-lane row group (STAGE 2 only)
  auto LNPACK = [&](bf16x8 in)->bf16x8{
    float f[8];
    #pragma unroll
    for (int q=0;q<8;q++) f[q] = (float)in[q];
    float s = ((f[0]+f[1])+(f[2]+f[3])) + ((f[4]+f[5])+(f[6]+f[7]));
    float qq = f[0]*f[0]+f[1]*f[1]+f[2]*f[2]+f[3]*f[3]
             + f[4]*f[4]+f[5]*f[5]+f[6]*f[6]+f[7]*f[7];
    #pragma unroll
    for (int m=1; m<32; m<<=1){ s += __shfl_xor(s, m); qq += __shfl_xor(qq, m); }
    float mean = s * (1.f/256.f);
    float rstd = rsqrtf(qq*(1.f/256.f) - mean*mean + 1e-5f);
    bf16x8 o;
    o[0] = (__bf16)fmaxf((f[0]-mean)*rstd*lg0.x + lb0.x, 0.f);
    o[1] = (__bf16)fmaxf((f[1]-mean)*rstd*lg0.y + lb0.y, 0.f);
    o[2] = (__bf16)fmaxf((f[2]-mean)*rstd*lg0.z + lb0.z, 0.f);
    o[3] = (__bf16)fmaxf((f[3]-mean)*rstd*lg0.w + lb0.w, 0.f);
    o[4] = (__bf16)fmaxf((f[4]-mean)*rstd*lg1.x + lb1.x, 0.f);
    o[5] = (__bf16)fmaxf((f[5]-mean)*rstd*lg1.y + lb1.y, 0.f);
    o[6] = (__bf16)fmaxf((f[6]-mean)*rstd*lg1.z + lb1.z, 0.f);
    o[7] = (__bf16)fmaxf((f[7]-mean)*rstd*lg1.w + lb1.w, 0.f);
    return o;
  };

  LOADA(0);                                 // A(0) in flight

  // ---- one-time B-frag preload: 24 x 16B per lane ----
  bf16x8 bw[24];
  {
    const char* base = wBimg + (size_t)ns*98304 + o_l*64 + ((lk*16) ^ ((o_l&6)<<3));
    #pragma unroll
    for (int s=0; s<24; s++) bw[s] = *(const bf16x8*)(base + (size_t)s*4096);
  }
  float cbv = cb[och];

  for (int task=0; task<8; task++){
    int tbase = (tg*8 + task)*32;

    // ---- regs -> smA (swizzled); STAGE2: LN+relu inline; zero halo rows ----
    #pragma unroll
    for (int j=0; j<4; j++){
      int gi = tid + j*256;
      int r = gi >> 5, sg = gi & 31;
      bool ok = ((unsigned)(tbase + r - 1) < (unsigned)Tn);
      bf16x8 val;
      if (STAGE==1){
        val[0]=(__bf16)va[j].x; val[1]=(__bf16)va[j].y; val[2]=(__bf16)va[j].z; val[3]=(__bf16)va[j].w;
        val[4]=(__bf16)vb4[j].x; val[5]=(__bf16)vb4[j].y; val[6]=(__bf16)vb4[j].z; val[7]=(__bf16)vb4[j].w;
      } else {
        val = LNPACK(vv[j]);
      }
      if (!ok){
        #pragma unroll
        for (int q=0;q<8;q++) val[q] = (__bf16)0.f;
      }
      *(bf16x8*)(smA + r*512 + ((sg*16) ^ ((r&7)<<4))) = val;
    }
    if (tid < 64){
      int gi = 1024 + tid;
      int r = gi >> 5, sg = gi & 31;
      bool ok = ((unsigned)(tbase + r - 1) < (unsigned)Tn);
      bf16x8 val;
      if (STAGE==1){
        val[0]=(__bf16)ta0.x; val[1]=(__bf16)ta0.y; val[2]=(__bf16)ta0.z; val[3]=(__bf16)ta0.w;
        val[4]=(__bf16)ta1.x; val[5]=(__bf16)ta1.y; val[6]=(__bf16)ta1.z; val[7]=(__bf16)ta1.w;
      } else {
        val = LNPACK(tv);
      }
      if (!ok){
        #pragma unroll
        for (int q=0;q<8;q++) val[q] = (__bf16)0.f;
      }
      *(bf16x8*)(smA + r*512 + ((sg*16) ^ ((r&7)<<4))) = val;
    }
    __syncthreads();           // B1: smA ready; prev copy-out reads drained

    if (task+1 < 8) LOADA(task+1);   // next A-tile in flight across K-loop

    // ---- K-loop: LDS A-reads + reg-B MFMA, no barriers ----
    f32x4 acc[2];
    acc[0] = (f32x4){0.f,0.f,0.f,0.f};
    acc[1] = (f32x4){0.f,0.f,0.f,0.f};
    #pragma unroll
    for (int s=0; s<24; s++){
      int k3 = s >> 3, c = s & 7;
      #pragma unroll
      for (int mf=0; mf<2; mf++){
        int row = mf*16 + lm + k3;
        bf16x8 af = *(const bf16x8*)(smA + row*512 + ((((c*4+lk)*16)) ^ ((row&7)<<4)));
        acc[mf] = __builtin_amdgcn_mfma_f32_16x16x32_bf16(af, bw[s], acc[mf], 0, 0, 0);
      }
    }

    // ---- acc -> smY [32 rows][64 ch] bf16 ----
    #pragma unroll
    for (int mf=0; mf<2; mf++)
      #pragma unroll
      for (int j=0; j<4; j++){
        int row = mf*16 + lk*4 + j;
        *(__bf16*)(smY + row*128 + o_l*2) = (__bf16)(acc[mf][j] + cbv);
      }
    __syncthreads();           // B2: smA reads + smY writes done

    // ---- coalesced copy-out: one bf16x8 per thread ----
    {
      int row = tid >> 3, ch = (tid & 7)*8;
      bf16x8 val = *(const bf16x8*)(smY + row*128 + ch*2);
      *(bf16x8*)(yb + ((size_t)b*Tn + tbase + row)*256 + ns*64 + ch) = val;
    }
  }
}

// ======== LN2 + linear: LN in swizzled LDS + MFMA linear ========
__global__ __launch_bounds__(256) void k_ln2lin(
    const __bf16* __restrict__ yb, const float* __restrict__ g,
    const float* __restrict__ be, const char* __restrict__ lwB,
    const float* __restrict__ lb, const int* __restrict__ mel,
    float* __restrict__ pspec, float* __restrict__ p2)
{
  __shared__ __align__(16) char smY[64*512];
  __shared__ __align__(16) char smLW[16384];
  const int tid = threadIdx.x, b = blockIdx.y, tbase = blockIdx.x*64;
  const int w = tid >> 6, l = tid & 63, lm = l & 15, lk = l >> 4;

  {
    const char* src = lwB + tid*16;
    char* dst = smLW + tid*16;
    #pragma unroll
    for (int r=0;r<4;r++) gld_lds16(src + r*4096, dst + r*4096);
  }
  bf16x8 yv[8];
  #pragma unroll
  for (int j=0;j<8;j++){
    int gi = tid + j*256;
    int r = gi >> 5, sg = gi & 31;
    yv[j] = *(const bf16x8*)(yb + ((size_t)b*Tn + tbase + r)*256 + sg*8);
  }
  #pragma unroll
  for (int j=0;j<8;j++){
    int gi = tid + j*256;
    int r = gi >> 5, sg = gi & 31;
    *(bf16x8*)(smY + r*512 + ((sg*16) ^ ((r&7)<<4))) = yv[j];
  }
  __syncthreads();

  float4 gv = ((const float4*)g)[l];
  float4 bv = ((const float4*)be)[l];
  for (int rr=0; rr<16; rr++){
    int row = w*16 + rr;
    char* p = smY + row*512 + ((((l>>1)*16)) ^ ((row&7)<<4)) + (l&1)*8;
    bf16x4 v = *(const bf16x4*)p;
    float f0=(float)v[0], f1=(float)v[1], f2=(float)v[2], f3=(float)v[3];
    float s = (f0+f1)+(f2+f3);
    float q = f0*f0+f1*f1+f2*f2+f3*f3;
    #pragma unroll
    for (int m=1; m<64; m<<=1){ s += __shfl_xor(s, m); q += __shfl_xor(q, m); }
    float mean = s * (1.f/256.f);
    float rstd = rsqrtf(q*(1.f/256.f) - mean*mean + 1e-5f);
    bf16x4 hv;
    hv[0] = (__bf16)fmaxf((f0-mean)*rstd*gv.x + bv.x, 0.f);
    hv[1] = (__bf16)fmaxf((f1-mean)*rstd*gv.y + bv.y, 0.f);
    hv[2] = (__bf16)fmaxf((f2-mean)*rstd*gv.z + bv.z, 0.f);
    hv[3] = (__bf16)fmaxf((f3-mean)*rstd*gv.w + bv.w, 0.f);
    *(bf16x4*)p = hv;
  }
  __syncthreads();

  f32x4 acc[2];
  acc[0] = (f32x4){0.f,0.f,0.f,0.f};
  acc[1] = (f32x4){0.f,0.f,0.f,0.f};
  #pragma unroll
  for (int ks=0; ks<8; ks++){
    int row = w*16 + lm;
    bf16x8 af = *(const bf16x8*)(smY + row*512 + ((((ks*4+lk)*16)) ^ ((row&7)<<4)));
    #pragma unroll
    for (int nf=0; nf<2; nf++){
      int col = nf*16 + lm;
      bf16x8 bfr = *(const bf16x8*)(smLW + col*512 + (((ks*64 + lk*16)) ^ ((col&7)<<4)));
      acc[nf] = __builtin_amdgcn_mfma_f32_16x16x32_bf16(af, bfr, acc[nf], 0, 0, 0);
    }
  }

  int len = mel[b];
  #pragma unroll
  for (int nf=0; nf<2; nf++){
    int o = nf*16 + lm;
    float lbv = (o < 22) ? lb[o] : 0.f;
    #pragma unroll
    for (int j=0; j<4; j++){
      int row = w*16 + lk*4 + j;
      int t = tbase + row;
      float v = acc[nf][j] + lbv;
      if (o < 20)      pspec[((size_t)b*Tn + t)*20 + o] = (t<len) ? v : 0.f;
      else if (o < 22) p2[((size_t)b*Tn + t)*2 + (o-20)] = v;   // unmasked
    }
  }
}

// ---------------- predictor_params ----------------
__global__ void k_pparams(const float* __restrict__ p2, float* __restrict__ ppar){
  __shared__ float r0[256], r1[256];
  int b = blockIdx.x, tid = threadIdx.x;
  float s0=0.f, s1=0.f;
  for (int t=tid; t<Tn; t+=256){
    s0 += p2[((size_t)b*Tn+t)*2];
    s1 += p2[((size_t)b*Tn+t)*2+1];
  }
  r0[tid]=s0; r1[tid]=s1; __syncthreads();
  for (int off=128; off; off>>=1){ if(tid<off){r0[tid]+=r0[tid+off]; r1[tid]+=r1[tid+off];} __syncthreads(); }
  if (tid==0){ ppar[2*b] = r0[0]*(1.f/Tn); ppar[2*b+1] = r1[0]*(1.f/Tn); }
}

// ---------------- quantize + embedding gather ----------------
__global__ void k_embed(const float* __restrict__ target, const float* __restrict__ alpha,
                        const int* __restrict__ mel, const float* __restrict__ emb,
                        float* __restrict__ out){
  int row  = blockIdx.x*4 + (threadIdx.x>>6);
  int lane = threadIdx.x & 63;
  int b = row >> 11, t = row & (Tn-1);
  int qid = 0;
  if (t < mel[b]){
    float q = target[row]*alpha[b];
    q = fminf(fmaxf(q, 0.f), 800.f);
    qid = (int)rintf(q/3.125f) + 1;
  }
  float4 v = ((const float4*)(emb + (size_t)qid*256))[lane];
  ((float4*)(out + (size_t)row*256))[lane] = v;
}

extern "C" void kernel_launch(void* const* d_in, const int* in_sizes, int n_in,
                              void* d_out, int out_size, void* d_ws, size_t ws_size,
                              hipStream_t stream) {
  const float* x      = (const float*)d_in[0];
  const float* alpha  = (const float*)d_in[1];
  const float* target = (const float*)d_in[2];
  const int*   mel    = (const int*)  d_in[3];
  const float* w1     = (const float*)d_in[4];
  const float* b1     = (const float*)d_in[5];
  const float* g1     = (const float*)d_in[6];
  const float* be1    = (const float*)d_in[7];
  const float* w2     = (const float*)d_in[8];
  const float* b2     = (const float*)d_in[9];
  const float* g2     = (const float*)d_in[10];
  const float* be2    = (const float*)d_in[11];
  const float* lw     = (const float*)d_in[12];
  const float* lb     = (const float*)d_in[13];
  const float* emb    = (const float*)d_in[14];
  float* out = (float*)d_out;
  char*  wsb = (char*)d_ws;

  char*   wb1 = wsb + OB_WB1;
  char*   wb2 = wsb + OB_WB2;
  char*   lwB = wsb + OB_LWB;
  float*  p2  = (float*)(wsb + OB_P2);
  float*  X   = (float*)(wsb + OB_X);
  float*  Y1  = (float*)(wsb + OB_Y1);
  __bf16* Y   = (__bf16*)(wsb + OB_Y);

  k_fwd_dft<<<Bn*64, 256, 0, stream>>>(target, mel, X, out + O_TPAR);
  k_idft1<<<dim3(32, Bn), 256, 0, stream>>>(X, Y1);
  k_idft2<<<dim3(64, Bn), 256, 0, stream>>>(Y1, mel, out + O_TSPEC);
  k_prep_w<<<1568, 256, 0, stream>>>(w1, w2, lw, wb1, wb2, lwB);
  k_conv_gemm<1><<<dim3(8, 4, Bn), 256, 0, stream>>>(x, wb1, b1, nullptr, nullptr, Y);
  k_conv_gemm<2><<<dim3(8, 4, Bn), 256, 0, stream>>>(Y, wb2, b2, g1, be1, Y);
  k_ln2lin<<<dim3(Tn/64, Bn), 256, 0, stream>>>(Y, g2, be2, lwB, lb, mel,
                                                out + O_PSPEC, p2);
  k_pparams<<<Bn, 256, 0, stream>>>(p2, out + O_PPAR);
  k_embed<<<Bn*Tn/4, 256, 0, stream>>>(target, alpha, mel, emb, out + O_EMB);
}

// Round 18
// 115.471 us; speedup vs baseline: 1.0529x; 1.0529x over previous
//
#include <hip/hip_runtime.h>
#include <hip/hip_bf16.h>
#include <math.h>

#define Bn 16
#define Tn 2048
#define Wn 10
constexpr float PI_F = 3.14159265358979323846f;

typedef __bf16 bf16x8 __attribute__((ext_vector_type(8)));
typedef __bf16 bf16x4 __attribute__((ext_vector_type(4)));
typedef float  f32x4  __attribute__((ext_vector_type(4)));

// ---- output offsets (floats) ----
constexpr size_t O_EMB   = 0;
constexpr size_t O_PSPEC = (size_t)Bn*Tn*256;            // 8388608
constexpr size_t O_PPAR  = O_PSPEC + (size_t)Bn*Tn*20;   // 9043968
constexpr size_t O_TSPEC = O_PPAR + 2*Bn;                // 9044000
constexpr size_t O_TPAR  = O_TSPEC + (size_t)Bn*Tn*20;   // 9699360

// ---- workspace BYTE offsets ----
constexpr size_t OB_WB1  = 0;
constexpr size_t OB_WB2  = OB_WB1 + 393216;
constexpr size_t OB_LWB  = OB_WB2 + 393216;               // 16KB lw B-frag image
constexpr size_t OB_H1   = OB_LWB + 16384;                // B*T*256 bf16 = 16MB
constexpr size_t OB_SCR  = OB_H1 + 16777216;              // 16MB scratch union:
constexpr size_t OB_X    = OB_SCR;
constexpr size_t OB_Y1   = OB_SCR + 1441792;
constexpr size_t OB_Y    = OB_SCR;

__device__ __forceinline__ void gld_lds16(const void* g, void* l){
  __builtin_amdgcn_global_load_lds(
      (const __attribute__((address_space(1))) unsigned int*)g,
      (__attribute__((address_space(3))) unsigned int*)l, 16, 0, 0);
}

// ---- weight prep (conv images + lw image, single launch) ----
__global__ void k_prep_w(const float* __restrict__ w1, const float* __restrict__ w2,
                         const float* __restrict__ lw,
                         char* __restrict__ wb1, char* __restrict__ wb2,
                         char* __restrict__ lwB){
  int idx = blockIdx.x*256 + threadIdx.x;     // 401408 = 2*196608 + 8192
  if (idx >= 393216){
    int r2 = idx - 393216;
    int col = r2 >> 8, k = r2 & 255;
    float v = (col < 22) ? lw[col*256 + k] : 0.f;
    size_t off = (size_t)col*512 + ((((k>>3)*16)) ^ ((col&7)<<4)) + ((k&7)<<1);
    *(__bf16*)(lwB + off) = (__bf16)v;
    return;
  }
  const float* w = w1; char* wb = wb1;
  if (idx >= 196608){ idx -= 196608; w = w2; wb = wb2; }
  int ns   = idx / 49152;
  int rem  = idx - ns*49152;
  int s    = rem >> 11;
  int rem2 = rem & 2047;
  int o_l  = rem2 >> 5;
  int kk   = rem2 & 31;
  int o  = ns*64 + o_l;
  int k3 = s >> 3;
  int i  = (s & 7)*32 + kk;
  float v = w[((size_t)o*256 + i)*3 + k3];
  size_t off = (size_t)ns*98304 + (size_t)s*4096 + o_l*64
             + ((((kk>>3)<<4)) ^ ((o_l&6)<<3)) + ((kk&7)<<1);
  *(__bf16*)(wb + off) = (__bf16)v;
}

// ======== forward DFT with fused per-batch stats; also zeroes ppar ========
__global__ void k_fwd_dft(const float* __restrict__ target, const int* __restrict__ mel,
                          float* __restrict__ X, float* __restrict__ tpar,
                          float* __restrict__ ppar){
  __shared__ float cbuf[Tn];
  __shared__ float2 tw[Tn];
  __shared__ float red[256];
  __shared__ float msh[2];
  int b = blockIdx.x >> 6, kc = blockIdx.x & 63, tid = threadIdx.x;
  int len = mel[b];
  float lenf = (float)len;
  float s = 0.f;
  for (int n=tid; n<Tn; n+=256){ float v = target[(size_t)b*Tn+n]; cbuf[n] = v; s += v; }
  red[tid]=s; __syncthreads();
  for (int off=128; off; off>>=1){ if(tid<off) red[tid]+=red[tid+off]; __syncthreads(); }
  if (tid==0) msh[0] = red[0]/lenf;
  __syncthreads();
  float mean = msh[0];
  float s2 = 0.f;
  for (int n=tid; n<Tn; n+=256){ float d = (n<len)?(cbuf[n]-mean):0.f; s2 += d*d; }
  red[tid]=s2; __syncthreads();
  for (int off=128; off; off>>=1){ if(tid<off) red[tid]+=red[tid+off]; __syncthreads(); }
  if (tid==0) msh[1] = sqrtf(red[0]/(lenf-1.f));
  __syncthreads();
  float stdv = msh[1];
  if (kc==0 && tid==0){
    tpar[2*b] = mean; tpar[2*b+1] = stdv;
    ppar[2*b] = 0.f;  ppar[2*b+1] = 0.f;     // zero for ln2lin atomics (re-done每replay)
  }
  float istd = 1.f/stdv;
  for (int n=tid; n<Tn; n+=256){
    float sn, cs;
    sincosf((2.f*PI_F/Tn)*n, &sn, &cs);
    tw[n] = make_float2(cs, sn);
    cbuf[n] = (n<len) ? (cbuf[n]-mean)*istd : 0.f;
  }
  __syncthreads();
  int k  = (kc<<4) | (tid>>4);
  int tl = tid & 15;
  float xr=0.f, xi=0.f;
  for (int t=tl; t<Tn; t+=16){
    int n = (k*t) & (Tn-1);
    float2 w = tw[n];
    float cv = cbuf[t];
    xr += cv*w.x;
    xi -= cv*w.y;
  }
  #pragma unroll
  for (int m=1; m<16; m<<=1){ xr += __shfl_xor(xr,m); xi += __shfl_xor(xi,m); }
  if (tl==0){ X[2*(b*1024+k)] = xr; X[2*(b*1024+k)+1] = xi; }
}

// ======== inverse DFT stage 1, fused psi-multiply ========
__global__ __launch_bounds__(256) void k_idft1(const float* __restrict__ X,
                                               float* __restrict__ Y1){
  __shared__ float zc[640];
  __shared__ float2 tw64[64];
  int c = blockIdx.x, b = blockIdx.y, tid = threadIdx.x;
  if (tid < 64){
    float sn, cs;
    sincosf((2.f*PI_F/64.f)*tid, &sn, &cs);
    tw64[tid] = make_float2(cs, sn);
  }
  const float pref = 0.7511255444649425f;  // pi^-0.25
  for (int i = tid; i < 640; i += 256){
    int a = i / 20, j = i - a*20;
    int k = a*32 + c;
    int sidx = j >> 1;
    float omega = (2.f*PI_F/Tn)*k;
    float sc = expf(0.4f*(float)sidx);
    float arg = sc*omega - 6.0f;
    float psi = (k>0) ? pref*sqrtf(2.f*PI_F*sc)*expf(-0.5f*arg*arg)*(1.f/Tn) : 0.f;
    float xv = X[2*((size_t)b*1024 + k) + (j&1)];
    zc[i] = xv * psi;
  }
  __syncthreads();
  int u = tid & 63, g = tid >> 6;
  float* dst = Y1 + (((size_t)b*32 + c)*64 + u)*20;
  for (int s = g; s < 10; s += 4){
    float yr = 0.f, yi = 0.f;
    #pragma unroll
    for (int a = 0; a < 32; a++){
      float2 w = tw64[(a*u) & 63];
      float zr = zc[a*20 + 2*s], zi = zc[a*20 + 2*s + 1];
      yr += zr*w.x - zi*w.y;
      yi += zr*w.y + zi*w.x;
    }
    dst[2*s]   = yr;
    dst[2*s+1] = yi;
  }
}

__global__ __launch_bounds__(256) void k_idft2(const float* __restrict__ Y1,
                                               const int* __restrict__ mel,
                                               float* __restrict__ tspec){
  __shared__ float2 tw[Tn];
  __shared__ float ys[640];
  int u = blockIdx.x, b = blockIdx.y, tid = threadIdx.x;
  for (int n = tid; n < Tn; n += 256){
    float sn, cs;
    sincosf((2.f*PI_F/Tn)*n, &sn, &cs);
    tw[n] = make_float2(cs, sn);
  }
  for (int i = tid; i < 640; i += 256){
    int c = i / 20, j = i - c*20;
    ys[i] = Y1[(((size_t)b*32 + c)*64 + u)*20 + j];
  }
  __syncthreads();
  int len = mel[b];
  int j = tid >> 3, l8 = tid & 7;
  int t = u + (j << 6);
  if (l8 < 5){
    #pragma unroll
    for (int sp = 0; sp < 2; sp++){
      int s = l8 + sp*5;
      float wr = 0.f, wi = 0.f;
      #pragma unroll
      for (int c = 0; c < 32; c++){
        float2 w = tw[(c*t) & (Tn-1)];
        float yr = ys[c*20 + 2*s], yi = ys[c*20 + 2*s + 1];
        wr += yr*w.x - yi*w.y;
        wi += yr*w.y + yi*w.x;
      }
      bool ok = (t < len);
      tspec[((size_t)b*Tn + t)*20 + s]      = ok ? wr : 0.f;
      tspec[((size_t)b*Tn + t)*20 + s + 10] = ok ? wi : 0.f;
    }
  }
}

// ======== conv GEMM v3 (R14/R16 proven): reg-B, 8 tasks/block ========
template<int STAGE>
__global__ __launch_bounds__(256) void k_conv_gemm(
    const void* __restrict__ in_v, const char* __restrict__ wBimg,
    const float* __restrict__ cb, __bf16* __restrict__ yb)
{
  __shared__ char smA[34*512];              // 17408 B
  __shared__ char smY[32*128];              // 4096 B
  const int tid = threadIdx.x;
  const int tg = blockIdx.x, ns = blockIdx.y, b = blockIdx.z;
  const int w = tid >> 6, l = tid & 63, lm = l & 15, lk = l >> 4;
  const int o_l = w*16 + lm;
  const int och = ns*64 + o_l;

  float4 va[4], vb4[4]; bf16x8 vv[4];
  float4 ta0, ta1; bf16x8 tv;

  auto LOADA = [&](int task){
    int tbase = (tg*8 + task)*32;
    #pragma unroll
    for (int j=0; j<4; j++){
      int gi = tid + j*256;
      int r = gi >> 5, sg = gi & 31;
      int tc = min(max(tbase + r - 1, 0), Tn-1);
      if (STAGE==1){
        const float4* src = (const float4*)((const float*)in_v + ((size_t)b*Tn + tc)*256 + sg*8);
        va[j] = src[0]; vb4[j] = src[1];
      } else {
        vv[j] = *(const bf16x8*)((const __bf16*)in_v + ((size_t)b*Tn + tc)*256 + sg*8);
      }
    }
    if (tid < 64){
      int gi = 1024 + tid;
      int r = gi >> 5, sg = gi & 31;
      int tc = min(max(tbase + r - 1, 0), Tn-1);
      if (STAGE==1){
        const float4* src = (const float4*)((const float*)in_v + ((size_t)b*Tn + tc)*256 + sg*8);
        ta0 = src[0]; ta1 = src[1];
      } else {
        tv = *(const bf16x8*)((const __bf16*)in_v + ((size_t)b*Tn + tc)*256 + sg*8);
      }
    }
  };

  LOADA(0);                                 // A(0) in flight

  // ---- one-time B-frag preload: 24 x 16B per lane ----
  bf16x8 bw[24];
  {
    const char* base = wBimg + (size_t)ns*98304 + o_l*64 + ((lk*16) ^ ((o_l&6)<<3));
    #pragma unroll
    for (int s=0; s<24; s++) bw[s] = *(const bf16x8*)(base + (size_t)s*4096);
  }
  float cbv = cb[och];

  for (int task=0; task<8; task++){
    int tbase = (tg*8 + task)*32;

    // ---- regs -> smA (swizzled); zero halo rows outside [0,Tn) ----
    #pragma unroll
    for (int j=0; j<4; j++){
      int gi = tid + j*256;
      int r = gi >> 5, sg = gi & 31;
      bool ok = ((unsigned)(tbase + r - 1) < (unsigned)Tn);
      bf16x8 val;
      if (STAGE==1){
        val[0]=(__bf16)va[j].x; val[1]=(__bf16)va[j].y; val[2]=(__bf16)va[j].z; val[3]=(__bf16)va[j].w;
        val[4]=(__bf16)vb4[j].x; val[5]=(__bf16)vb4[j].y; val[6]=(__bf16)vb4[j].z; val[7]=(__bf16)vb4[j].w;
      } else val = vv[j];
      if (!ok){
        #pragma unroll
        for (int q=0;q<8;q++) val[q] = (__bf16)0.f;
      }
      *(bf16x8*)(smA + r*512 + ((sg*16) ^ ((r&7)<<4))) = val;
    }
    if (tid < 64){
      int gi = 1024 + tid;
      int r = gi >> 5, sg = gi & 31;
      bool ok = ((unsigned)(tbase + r - 1) < (unsigned)Tn);
      bf16x8 val;
      if (STAGE==1){
        val[0]=(__bf16)ta0.x; val[1]=(__bf16)ta0.y; val[2]=(__bf16)ta0.z; val[3]=(__bf16)ta0.w;
        val[4]=(__bf16)ta1.x; val[5]=(__bf16)ta1.y; val[6]=(__bf16)ta1.z; val[7]=(__bf16)ta1.w;
      } else val = tv;
      if (!ok){
        #pragma unroll
        for (int q=0;q<8;q++) val[q] = (__bf16)0.f;
      }
      *(bf16x8*)(smA + r*512 + ((sg*16) ^ ((r&7)<<4))) = val;
    }
    __syncthreads();           // B1: smA ready; prev copy-out reads drained

    if (task+1 < 8) LOADA(task+1);   // next A-tile in flight across K-loop

    // ---- K-loop: LDS A-reads + reg-B MFMA, no barriers ----
    f32x4 acc[2];
    acc[0] = (f32x4){0.f,0.f,0.f,0.f};
    acc[1] = (f32x4){0.f,0.f,0.f,0.f};
    #pragma unroll
    for (int s=0; s<24; s++){
      int k3 = s >> 3, c = s & 7;
      #pragma unroll
      for (int mf=0; mf<2; mf++){
        int row = mf*16 + lm + k3;
        bf16x8 af = *(const bf16x8*)(smA + row*512 + ((((c*4+lk)*16)) ^ ((row&7)<<4)));
        acc[mf] = __builtin_amdgcn_mfma_f32_16x16x32_bf16(af, bw[s], acc[mf], 0, 0, 0);
      }
    }

    // ---- acc -> smY [32 rows][64 ch] bf16 ----
    #pragma unroll
    for (int mf=0; mf<2; mf++)
      #pragma unroll
      for (int j=0; j<4; j++){
        int row = mf*16 + lk*4 + j;
        *(__bf16*)(smY + row*128 + o_l*2) = (__bf16)(acc[mf][j] + cbv);
      }
    __syncthreads();           // B2: smA reads + smY writes done

    // ---- coalesced copy-out: one bf16x8 per thread ----
    {
      int row = tid >> 3, ch = (tid & 7)*8;
      bf16x8 val = *(const bf16x8*)(smY + row*128 + ch*2);
      *(bf16x8*)(yb + ((size_t)b*Tn + tbase + row)*256 + ns*64 + ch) = val;
    }
  }
}

// ======== LN1: row-wise LN+relu, y bf16 -> h1 bf16 ========
__global__ __launch_bounds__(256) void k_ln1(
    const __bf16* __restrict__ yb, const float* __restrict__ g,
    const float* __restrict__ be, __bf16* __restrict__ h)
{
  int w = threadIdx.x >> 6, l = threadIdx.x & 63;
  float4 gv = ((const float4*)g)[l];
  float4 bv = ((const float4*)be)[l];
  #pragma unroll
  for (int rr=0; rr<4; rr++){
    int row = blockIdx.x*16 + w*4 + rr;
    bf16x4 v = *(const bf16x4*)(yb + (size_t)row*256 + l*4);
    float f0=(float)v[0], f1=(float)v[1], f2=(float)v[2], f3=(float)v[3];
    float s = (f0+f1)+(f2+f3);
    float q = f0*f0+f1*f1+f2*f2+f3*f3;
    #pragma unroll
    for (int m=1; m<64; m<<=1){ s += __shfl_xor(s, m); q += __shfl_xor(q, m); }
    float mean = s * (1.f/256.f);
    float rstd = rsqrtf(q*(1.f/256.f) - mean*mean + 1e-5f);
    bf16x4 hv;
    hv[0] = (__bf16)fmaxf((f0-mean)*rstd*gv.x + bv.x, 0.f);
    hv[1] = (__bf16)fmaxf((f1-mean)*rstd*gv.y + bv.y, 0.f);
    hv[2] = (__bf16)fmaxf((f2-mean)*rstd*gv.z + bv.z, 0.f);
    hv[3] = (__bf16)fmaxf((f3-mean)*rstd*gv.w + bv.w, 0.f);
    *(bf16x4*)(h + (size_t)row*256 + l*4) = hv;
  }
}

// ======== LN2 + linear + fused predictor_params reduce ========
__global__ __launch_bounds__(256) void k_ln2lin(
    const __bf16* __restrict__ yb, const float* __restrict__ g,
    const float* __restrict__ be, const char* __restrict__ lwB,
    const float* __restrict__ lb, const int* __restrict__ mel,
    float* __restrict__ pspec, float* __restrict__ ppar)
{
  __shared__ __align__(16) char smY[64*512];
  __shared__ __align__(16) char smLW[16384];
  __shared__ float pp[4][16][2];
  const int tid = threadIdx.x, b = blockIdx.y, tbase = blockIdx.x*64;
  const int w = tid >> 6, l = tid & 63, lm = l & 15, lk = l >> 4;

  {
    const char* src = lwB + tid*16;
    char* dst = smLW + tid*16;
    #pragma unroll
    for (int r=0;r<4;r++) gld_lds16(src + r*4096, dst + r*4096);
  }
  bf16x8 yv[8];
  #pragma unroll
  for (int j=0;j<8;j++){
    int gi = tid + j*256;
    int r = gi >> 5, sg = gi & 31;
    yv[j] = *(const bf16x8*)(yb + ((size_t)b*Tn + tbase + r)*256 + sg*8);
  }
  #pragma unroll
  for (int j=0;j<8;j++){
    int gi = tid + j*256;
    int r = gi >> 5, sg = gi & 31;
    *(bf16x8*)(smY + r*512 + ((sg*16) ^ ((r&7)<<4))) = yv[j];
  }
  __syncthreads();

  float4 gv = ((const float4*)g)[l];
  float4 bv = ((const float4*)be)[l];
  for (int rr=0; rr<16; rr++){
    int row = w*16 + rr;
    char* p = smY + row*512 + ((((l>>1)*16)) ^ ((row&7)<<4)) + (l&1)*8;
    bf16x4 v = *(const bf16x4*)p;
    float f0=(float)v[0], f1=(float)v[1], f2=(float)v[2], f3=(float)v[3];
    float s = (f0+f1)+(f2+f3);
    float q = f0*f0+f1*f1+f2*f2+f3*f3;
    #pragma unroll
    for (int m=1; m<64; m<<=1){ s += __shfl_xor(s, m); q += __shfl_xor(q, m); }
    float mean = s * (1.f/256.f);
    float rstd = rsqrtf(q*(1.f/256.f) - mean*mean + 1e-5f);
    bf16x4 hv;
    hv[0] = (__bf16)fmaxf((f0-mean)*rstd*gv.x + bv.x, 0.f);
    hv[1] = (__bf16)fmaxf((f1-mean)*rstd*gv.y + bv.y, 0.f);
    hv[2] = (__bf16)fmaxf((f2-mean)*rstd*gv.z + bv.z, 0.f);
    hv[3] = (__bf16)fmaxf((f3-mean)*rstd*gv.w + bv.w, 0.f);
    *(bf16x4*)p = hv;
  }
  __syncthreads();

  f32x4 acc[2];
  acc[0] = (f32x4){0.f,0.f,0.f,0.f};
  acc[1] = (f32x4){0.f,0.f,0.f,0.f};
  #pragma unroll
  for (int ks=0; ks<8; ks++){
    int row = w*16 + lm;
    bf16x8 af = *(const bf16x8*)(smY + row*512 + ((((ks*4+lk)*16)) ^ ((row&7)<<4)));
    #pragma unroll
    for (int nf=0; nf<2; nf++){
      int col = nf*16 + lm;
      bf16x8 bfr = *(const bf16x8*)(smLW + col*512 + (((ks*64 + lk*16)) ^ ((col&7)<<4)));
      acc[nf] = __builtin_amdgcn_mfma_f32_16x16x32_bf16(af, bfr, acc[nf], 0, 0, 0);
    }
  }

  int len = mel[b];
  float psum = 0.f; int pcol = -1;
  #pragma unroll
  for (int nf=0; nf<2; nf++){
    int o = nf*16 + lm;
    float lbv = (o < 22) ? lb[o] : 0.f;
    #pragma unroll
    for (int j=0; j<4; j++){
      int row = w*16 + lk*4 + j;
      int t = tbase + row;
      float v = acc[nf][j] + lbv;
      if (o < 20)      pspec[((size_t)b*Tn + t)*20 + o] = (t<len) ? v : 0.f;
      else if (o < 22){ psum += v; pcol = o - 20; }   // unmasked mean input
    }
  }
  if (pcol >= 0) pp[w][lk][pcol] = psum;   // every (w,lk,pcol) slot written (lm==4/5)
  __syncthreads();
  if (tid < 2){
    float s = 0.f;
    #pragma unroll
    for (int a=0;a<4;a++)
      #pragma unroll
      for (int q=0;q<16;q++) s += pp[a][q][tid];
    atomicAdd(&ppar[2*b + tid], s * (1.f/Tn));
  }
}

// ---------------- quantize + embedding gather ----------------
__global__ void k_embed(const float* __restrict__ target, const float* __restrict__ alpha,
                        const int* __restrict__ mel, const float* __restrict__ emb,
                        float* __restrict__ out){
  int row  = blockIdx.x*4 + (threadIdx.x>>6);
  int lane = threadIdx.x & 63;
  int b = row >> 11, t = row & (Tn-1);
  int qid = 0;
  if (t < mel[b]){
    float q = target[row]*alpha[b];
    q = fminf(fmaxf(q, 0.f), 800.f);
    qid = (int)rintf(q/3.125f) + 1;
  }
  float4 v = ((const float4*)(emb + (size_t)qid*256))[lane];
  ((float4*)(out + (size_t)row*256))[lane] = v;
}

extern "C" void kernel_launch(void* const* d_in, const int* in_sizes, int n_in,
                              void* d_out, int out_size, void* d_ws, size_t ws_size,
                              hipStream_t stream) {
  const float* x      = (const float*)d_in[0];
  const float* alpha  = (const float*)d_in[1];
  const float* target = (const float*)d_in[2];
  const int*   mel    = (const int*)  d_in[3];
  const float* w1     = (const float*)d_in[4];
  const float* b1     = (const float*)d_in[5];
  const float* g1     = (const float*)d_in[6];
  const float* be1    = (const float*)d_in[7];
  const float* w2     = (const float*)d_in[8];
  const float* b2     = (const float*)d_in[9];
  const float* g2     = (const float*)d_in[10];
  const float* be2    = (const float*)d_in[11];
  const float* lw     = (const float*)d_in[12];
  const float* lb     = (const float*)d_in[13];
  const float* emb    = (const float*)d_in[14];
  float* out = (float*)d_out;
  char*  wsb = (char*)d_ws;

  char*   wb1 = wsb + OB_WB1;
  char*   wb2 = wsb + OB_WB2;
  char*   lwB = wsb + OB_LWB;
  __bf16* h1  = (__bf16*)(wsb + OB_H1);
  float*  X   = (float*)(wsb + OB_X);
  float*  Y1  = (float*)(wsb + OB_Y1);
  __bf16* Y   = (__bf16*)(wsb + OB_Y);

  k_fwd_dft<<<Bn*64, 256, 0, stream>>>(target, mel, X, out + O_TPAR, out + O_PPAR);
  k_idft1<<<dim3(32, Bn), 256, 0, stream>>>(X, Y1);
  k_idft2<<<dim3(64, Bn), 256, 0, stream>>>(Y1, mel, out + O_TSPEC);
  k_prep_w<<<1568, 256, 0, stream>>>(w1, w2, lw, wb1, wb2, lwB);
  k_conv_gemm<1><<<dim3(8, 4, Bn), 256, 0, stream>>>(x, wb1, b1, Y);
  k_ln1<<<Bn*Tn/16, 256, 0, stream>>>(Y, g1, be1, h1);
  k_conv_gemm<2><<<dim3(8, 4, Bn), 256, 0, stream>>>(h1, wb2, b2, Y);
  k_ln2lin<<<dim3(Tn/64, Bn), 256, 0, stream>>>(Y, g2, be2, lwB, lb, mel,
                                                out + O_PSPEC, out + O_PPAR);
  k_embed<<<Bn*Tn/4, 256, 0, stream>>>(target, alpha, mel, emb, out + O_EMB);
}

// Round 19
// 114.574 us; speedup vs baseline: 1.0611x; 1.0078x over previous
//
#include <hip/hip_runtime.h>
#include <hip/hip_bf16.h>
#include <math.h>

#define Bn 16
#define Tn 2048
#define Wn 10
constexpr float PI_F = 3.14159265358979323846f;

typedef __bf16 bf16x8 __attribute__((ext_vector_type(8)));
typedef __bf16 bf16x4 __attribute__((ext_vector_type(4)));
typedef float  f32x4  __attribute__((ext_vector_type(4)));

// ---- output offsets (floats) ----
constexpr size_t O_EMB   = 0;
constexpr size_t O_PSPEC = (size_t)Bn*Tn*256;            // 8388608
constexpr size_t O_PPAR  = O_PSPEC + (size_t)Bn*Tn*20;   // 9043968
constexpr size_t O_TSPEC = O_PPAR + 2*Bn;                // 9044000
constexpr size_t O_TPAR  = O_TSPEC + (size_t)Bn*Tn*20;   // 9699360

// ---- workspace BYTE offsets ----
constexpr size_t OB_WB1  = 0;
constexpr size_t OB_WB2  = OB_WB1 + 393216;
constexpr size_t OB_LWB  = OB_WB2 + 393216;               // 16KB lw B-frag image
constexpr size_t OB_H1   = OB_LWB + 16384;                // B*T*256 bf16 = 16MB
constexpr size_t OB_SCR  = OB_H1 + 16777216;              // 16MB scratch union:
constexpr size_t OB_X    = OB_SCR;
constexpr size_t OB_Y1   = OB_SCR + 1441792;
constexpr size_t OB_Y    = OB_SCR;

__device__ __forceinline__ void gld_lds16(const void* g, void* l){
  __builtin_amdgcn_global_load_lds(
      (const __attribute__((address_space(1))) unsigned int*)g,
      (__attribute__((address_space(3))) unsigned int*)l, 16, 0, 0);
}

// ---- weight prep (conv images + lw image, single launch) ----
__global__ void k_prep_w(const float* __restrict__ w1, const float* __restrict__ w2,
                         const float* __restrict__ lw,
                         char* __restrict__ wb1, char* __restrict__ wb2,
                         char* __restrict__ lwB){
  int idx = blockIdx.x*256 + threadIdx.x;     // 401408 = 2*196608 + 8192
  if (idx >= 393216){
    int r2 = idx - 393216;
    int col = r2 >> 8, k = r2 & 255;
    float v = (col < 22) ? lw[col*256 + k] : 0.f;
    size_t off = (size_t)col*512 + ((((k>>3)*16)) ^ ((col&7)<<4)) + ((k&7)<<1);
    *(__bf16*)(lwB + off) = (__bf16)v;
    return;
  }
  const float* w = w1; char* wb = wb1;
  if (idx >= 196608){ idx -= 196608; w = w2; wb = wb2; }
  int ns   = idx / 49152;
  int rem  = idx - ns*49152;
  int s    = rem >> 11;
  int rem2 = rem & 2047;
  int o_l  = rem2 >> 5;
  int kk   = rem2 & 31;
  int o  = ns*64 + o_l;
  int k3 = s >> 3;
  int i  = (s & 7)*32 + kk;
  float v = w[((size_t)o*256 + i)*3 + k3];
  size_t off = (size_t)ns*98304 + (size_t)s*4096 + o_l*64
             + ((((kk>>3)<<4)) ^ ((o_l&6)<<3)) + ((kk&7)<<1);
  *(__bf16*)(wb + off) = (__bf16)v;
}

// ======== forward DFT with fused per-batch stats; also zeroes ppar ========
__global__ void k_fwd_dft(const float* __restrict__ target, const int* __restrict__ mel,
                          float* __restrict__ X, float* __restrict__ tpar,
                          float* __restrict__ ppar){
  __shared__ float cbuf[Tn];
  __shared__ float2 tw[Tn];
  __shared__ float red[256];
  __shared__ float msh[2];
  int b = blockIdx.x >> 6, kc = blockIdx.x & 63, tid = threadIdx.x;
  int len = mel[b];
  float lenf = (float)len;
  float s = 0.f;
  for (int n=tid; n<Tn; n+=256){ float v = target[(size_t)b*Tn+n]; cbuf[n] = v; s += v; }
  red[tid]=s; __syncthreads();
  for (int off=128; off; off>>=1){ if(tid<off) red[tid]+=red[tid+off]; __syncthreads(); }
  if (tid==0) msh[0] = red[0]/lenf;
  __syncthreads();
  float mean = msh[0];
  float s2 = 0.f;
  for (int n=tid; n<Tn; n+=256){ float d = (n<len)?(cbuf[n]-mean):0.f; s2 += d*d; }
  red[tid]=s2; __syncthreads();
  for (int off=128; off; off>>=1){ if(tid<off) red[tid]+=red[tid+off]; __syncthreads(); }
  if (tid==0) msh[1] = sqrtf(red[0]/(lenf-1.f));
  __syncthreads();
  float stdv = msh[1];
  if (kc==0 && tid==0){
    tpar[2*b] = mean; tpar[2*b+1] = stdv;
    ppar[2*b] = 0.f;  ppar[2*b+1] = 0.f;     // zero for ln2lin atomics (every replay)
  }
  float istd = 1.f/stdv;
  for (int n=tid; n<Tn; n+=256){
    float sn, cs;
    sincosf((2.f*PI_F/Tn)*n, &sn, &cs);
    tw[n] = make_float2(cs, sn);
    cbuf[n] = (n<len) ? (cbuf[n]-mean)*istd : 0.f;
  }
  __syncthreads();
  int k  = (kc<<4) | (tid>>4);
  int tl = tid & 15;
  float xr=0.f, xi=0.f;
  for (int t=tl; t<Tn; t+=16){
    int n = (k*t) & (Tn-1);
    float2 w = tw[n];
    float cv = cbuf[t];
    xr += cv*w.x;
    xi -= cv*w.y;
  }
  #pragma unroll
  for (int m=1; m<16; m<<=1){ xr += __shfl_xor(xr,m); xi += __shfl_xor(xi,m); }
  if (tl==0){ X[2*(b*1024+k)] = xr; X[2*(b*1024+k)+1] = xi; }
}

// ======== inverse DFT stage 1, fused psi-multiply ========
__global__ __launch_bounds__(256) void k_idft1(const float* __restrict__ X,
                                               float* __restrict__ Y1){
  __shared__ float zc[640];
  __shared__ float2 tw64[64];
  int c = blockIdx.x, b = blockIdx.y, tid = threadIdx.x;
  if (tid < 64){
    float sn, cs;
    sincosf((2.f*PI_F/64.f)*tid, &sn, &cs);
    tw64[tid] = make_float2(cs, sn);
  }
  const float pref = 0.7511255444649425f;  // pi^-0.25
  for (int i = tid; i < 640; i += 256){
    int a = i / 20, j = i - a*20;
    int k = a*32 + c;
    int sidx = j >> 1;
    float omega = (2.f*PI_F/Tn)*k;
    float sc = expf(0.4f*(float)sidx);
    float arg = sc*omega - 6.0f;
    float psi = (k>0) ? pref*sqrtf(2.f*PI_F*sc)*expf(-0.5f*arg*arg)*(1.f/Tn) : 0.f;
    float xv = X[2*((size_t)b*1024 + k) + (j&1)];
    zc[i] = xv * psi;
  }
  __syncthreads();
  int u = tid & 63, g = tid >> 6;
  float* dst = Y1 + (((size_t)b*32 + c)*64 + u)*20;
  for (int s = g; s < 10; s += 4){
    float yr = 0.f, yi = 0.f;
    #pragma unroll
    for (int a = 0; a < 32; a++){
      float2 w = tw64[(a*u) & 63];
      float zr = zc[a*20 + 2*s], zi = zc[a*20 + 2*s + 1];
      yr += zr*w.x - zi*w.y;
      yi += zr*w.y + zi*w.x;
    }
    dst[2*s]   = yr;
    dst[2*s+1] = yi;
  }
}

__global__ __launch_bounds__(256) void k_idft2(const float* __restrict__ Y1,
                                               const int* __restrict__ mel,
                                               float* __restrict__ tspec){
  __shared__ float2 tw[Tn];
  __shared__ float ys[640];
  int u = blockIdx.x, b = blockIdx.y, tid = threadIdx.x;
  for (int n = tid; n < Tn; n += 256){
    float sn, cs;
    sincosf((2.f*PI_F/Tn)*n, &sn, &cs);
    tw[n] = make_float2(cs, sn);
  }
  for (int i = tid; i < 640; i += 256){
    int c = i / 20, j = i - c*20;
    ys[i] = Y1[(((size_t)b*32 + c)*64 + u)*20 + j];
  }
  __syncthreads();
  int len = mel[b];
  int j = tid >> 3, l8 = tid & 7;
  int t = u + (j << 6);
  if (l8 < 5){
    #pragma unroll
    for (int sp = 0; sp < 2; sp++){
      int s = l8 + sp*5;
      float wr = 0.f, wi = 0.f;
      #pragma unroll
      for (int c = 0; c < 32; c++){
        float2 w = tw[(c*t) & (Tn-1)];
        float yr = ys[c*20 + 2*s], yi = ys[c*20 + 2*s + 1];
        wr += yr*w.x - yi*w.y;
        wi += yr*w.y + yi*w.x;
      }
      bool ok = (t < len);
      tspec[((size_t)b*Tn + t)*20 + s]      = ok ? wr : 0.f;
      tspec[((size_t)b*Tn + t)*20 + s + 10] = ok ? wi : 0.f;
    }
  }
}

// ======== conv GEMM v3 (R14/R16 proven): reg-B, 8 tasks/block ========
template<int STAGE>
__global__ __launch_bounds__(256) void k_conv_gemm(
    const void* __restrict__ in_v, const char* __restrict__ wBimg,
    const float* __restrict__ cb, __bf16* __restrict__ yb)
{
  __shared__ char smA[34*512];              // 17408 B
  __shared__ char smY[32*128];              // 4096 B
  const int tid = threadIdx.x;
  const int tg = blockIdx.x, ns = blockIdx.y, b = blockIdx.z;
  const int w = tid >> 6, l = tid & 63, lm = l & 15, lk = l >> 4;
  const int o_l = w*16 + lm;
  const int och = ns*64 + o_l;

  float4 va[4], vb4[4]; bf16x8 vv[4];
  float4 ta0, ta1; bf16x8 tv;

  auto LOADA = [&](int task){
    int tbase = (tg*8 + task)*32;
    #pragma unroll
    for (int j=0; j<4; j++){
      int gi = tid + j*256;
      int r = gi >> 5, sg = gi & 31;
      int tc = min(max(tbase + r - 1, 0), Tn-1);
      if (STAGE==1){
        const float4* src = (const float4*)((const float*)in_v + ((size_t)b*Tn + tc)*256 + sg*8);
        va[j] = src[0]; vb4[j] = src[1];
      } else {
        vv[j] = *(const bf16x8*)((const __bf16*)in_v + ((size_t)b*Tn + tc)*256 + sg*8);
      }
    }
    if (tid < 64){
      int gi = 1024 + tid;
      int r = gi >> 5, sg = gi & 31;
      int tc = min(max(tbase + r - 1, 0), Tn-1);
      if (STAGE==1){
        const float4* src = (const float4*)((const float*)in_v + ((size_t)b*Tn + tc)*256 + sg*8);
        ta0 = src[0]; ta1 = src[1];
      } else {
        tv = *(const bf16x8*)((const __bf16*)in_v + ((size_t)b*Tn + tc)*256 + sg*8);
      }
    }
  };

  LOADA(0);                                 // A(0) in flight

  // ---- one-time B-frag preload: 24 x 16B per lane ----
  bf16x8 bw[24];
  {
    const char* base = wBimg + (size_t)ns*98304 + o_l*64 + ((lk*16) ^ ((o_l&6)<<3));
    #pragma unroll
    for (int s=0; s<24; s++) bw[s] = *(const bf16x8*)(base + (size_t)s*4096);
  }
  float cbv = cb[och];

  for (int task=0; task<8; task++){
    int tbase = (tg*8 + task)*32;

    // ---- regs -> smA (swizzled); zero halo rows outside [0,Tn) ----
    #pragma unroll
    for (int j=0; j<4; j++){
      int gi = tid + j*256;
      int r = gi >> 5, sg = gi & 31;
      bool ok = ((unsigned)(tbase + r - 1) < (unsigned)Tn);
      bf16x8 val;
      if (STAGE==1){
        val[0]=(__bf16)va[j].x; val[1]=(__bf16)va[j].y; val[2]=(__bf16)va[j].z; val[3]=(__bf16)va[j].w;
        val[4]=(__bf16)vb4[j].x; val[5]=(__bf16)vb4[j].y; val[6]=(__bf16)vb4[j].z; val[7]=(__bf16)vb4[j].w;
      } else val = vv[j];
      if (!ok){
        #pragma unroll
        for (int q=0;q<8;q++) val[q] = (__bf16)0.f;
      }
      *(bf16x8*)(smA + r*512 + ((sg*16) ^ ((r&7)<<4))) = val;
    }
    if (tid < 64){
      int gi = 1024 + tid;
      int r = gi >> 5, sg = gi & 31;
      bool ok = ((unsigned)(tbase + r - 1) < (unsigned)Tn);
      bf16x8 val;
      if (STAGE==1){
        val[0]=(__bf16)ta0.x; val[1]=(__bf16)ta0.y; val[2]=(__bf16)ta0.z; val[3]=(__bf16)ta0.w;
        val[4]=(__bf16)ta1.x; val[5]=(__bf16)ta1.y; val[6]=(__bf16)ta1.z; val[7]=(__bf16)ta1.w;
      } else val = tv;
      if (!ok){
        #pragma unroll
        for (int q=0;q<8;q++) val[q] = (__bf16)0.f;
      }
      *(bf16x8*)(smA + r*512 + ((sg*16) ^ ((r&7)<<4))) = val;
    }
    __syncthreads();           // B1: smA ready; prev copy-out reads drained

    if (task+1 < 8) LOADA(task+1);   // next A-tile in flight across K-loop

    // ---- K-loop: LDS A-reads + reg-B MFMA, no barriers ----
    f32x4 acc[2];
    acc[0] = (f32x4){0.f,0.f,0.f,0.f};
    acc[1] = (f32x4){0.f,0.f,0.f,0.f};
    #pragma unroll
    for (int s=0; s<24; s++){
      int k3 = s >> 3, c = s & 7;
      #pragma unroll
      for (int mf=0; mf<2; mf++){
        int row = mf*16 + lm + k3;
        bf16x8 af = *(const bf16x8*)(smA + row*512 + ((((c*4+lk)*16)) ^ ((row&7)<<4)));
        acc[mf] = __builtin_amdgcn_mfma_f32_16x16x32_bf16(af, bw[s], acc[mf], 0, 0, 0);
      }
    }

    // ---- acc -> smY [32 rows][64 ch] bf16 ----
    #pragma unroll
    for (int mf=0; mf<2; mf++)
      #pragma unroll
      for (int j=0; j<4; j++){
        int row = mf*16 + lk*4 + j;
        *(__bf16*)(smY + row*128 + o_l*2) = (__bf16)(acc[mf][j] + cbv);
      }
    __syncthreads();           // B2: smA reads + smY writes done

    // ---- coalesced copy-out: one bf16x8 per thread ----
    {
      int row = tid >> 3, ch = (tid & 7)*8;
      bf16x8 val = *(const bf16x8*)(smY + row*128 + ch*2);
      *(bf16x8*)(yb + ((size_t)b*Tn + tbase + row)*256 + ns*64 + ch) = val;
    }
  }
}

// ======== LN1: row-wise LN+relu, y bf16 -> h1 bf16 ========
__global__ __launch_bounds__(256) void k_ln1(
    const __bf16* __restrict__ yb, const float* __restrict__ g,
    const float* __restrict__ be, __bf16* __restrict__ h)
{
  int w = threadIdx.x >> 6, l = threadIdx.x & 63;
  float4 gv = ((const float4*)g)[l];
  float4 bv = ((const float4*)be)[l];
  #pragma unroll
  for (int rr=0; rr<4; rr++){
    int row = blockIdx.x*16 + w*4 + rr;
    bf16x4 v = *(const bf16x4*)(yb + (size_t)row*256 + l*4);
    float f0=(float)v[0], f1=(float)v[1], f2=(float)v[2], f3=(float)v[3];
    float s = (f0+f1)+(f2+f3);
    float q = f0*f0+f1*f1+f2*f2+f3*f3;
    #pragma unroll
    for (int m=1; m<64; m<<=1){ s += __shfl_xor(s, m); q += __shfl_xor(q, m); }
    float mean = s * (1.f/256.f);
    float rstd = rsqrtf(q*(1.f/256.f) - mean*mean + 1e-5f);
    bf16x4 hv;
    hv[0] = (__bf16)fmaxf((f0-mean)*rstd*gv.x + bv.x, 0.f);
    hv[1] = (__bf16)fmaxf((f1-mean)*rstd*gv.y + bv.y, 0.f);
    hv[2] = (__bf16)fmaxf((f2-mean)*rstd*gv.z + bv.z, 0.f);
    hv[3] = (__bf16)fmaxf((f3-mean)*rstd*gv.w + bv.w, 0.f);
    *(bf16x4*)(h + (size_t)row*256 + l*4) = hv;
  }
}

// ======== LN2 + linear + fused predictor_params reduce ========
__global__ __launch_bounds__(256) void k_ln2lin(
    const __bf16* __restrict__ yb, const float* __restrict__ g,
    const float* __restrict__ be, const char* __restrict__ lwB,
    const float* __restrict__ lb, const int* __restrict__ mel,
    float* __restrict__ pspec, float* __restrict__ ppar)
{
  __shared__ __align__(16) char smY[64*512];
  __shared__ __align__(16) char smLW[16384];
  __shared__ float pp[4][4][2];              // [wave][lk][col] — exactly what's written
  const int tid = threadIdx.x, b = blockIdx.y, tbase = blockIdx.x*64;
  const int w = tid >> 6, l = tid & 63, lm = l & 15, lk = l >> 4;

  {
    const char* src = lwB + tid*16;
    char* dst = smLW + tid*16;
    #pragma unroll
    for (int r=0;r<4;r++) gld_lds16(src + r*4096, dst + r*4096);
  }
  bf16x8 yv[8];
  #pragma unroll
  for (int j=0;j<8;j++){
    int gi = tid + j*256;
    int r = gi >> 5, sg = gi & 31;
    yv[j] = *(const bf16x8*)(yb + ((size_t)b*Tn + tbase + r)*256 + sg*8);
  }
  #pragma unroll
  for (int j=0;j<8;j++){
    int gi = tid + j*256;
    int r = gi >> 5, sg = gi & 31;
    *(bf16x8*)(smY + r*512 + ((sg*16) ^ ((r&7)<<4))) = yv[j];
  }
  __syncthreads();

  float4 gv = ((const float4*)g)[l];
  float4 bv = ((const float4*)be)[l];
  for (int rr=0; rr<16; rr++){
    int row = w*16 + rr;
    char* p = smY + row*512 + ((((l>>1)*16)) ^ ((row&7)<<4)) + (l&1)*8;
    bf16x4 v = *(const bf16x4*)p;
    float f0=(float)v[0], f1=(float)v[1], f2=(float)v[2], f3=(float)v[3];
    float s = (f0+f1)+(f2+f3);
    float q = f0*f0+f1*f1+f2*f2+f3*f3;
    #pragma unroll
    for (int m=1; m<64; m<<=1){ s += __shfl_xor(s, m); q += __shfl_xor(q, m); }
    float mean = s * (1.f/256.f);
    float rstd = rsqrtf(q*(1.f/256.f) - mean*mean + 1e-5f);
    bf16x4 hv;
    hv[0] = (__bf16)fmaxf((f0-mean)*rstd*gv.x + bv.x, 0.f);
    hv[1] = (__bf16)fmaxf((f1-mean)*rstd*gv.y + bv.y, 0.f);
    hv[2] = (__bf16)fmaxf((f2-mean)*rstd*gv.z + bv.z, 0.f);
    hv[3] = (__bf16)fmaxf((f3-mean)*rstd*gv.w + bv.w, 0.f);
    *(bf16x4*)p = hv;
  }
  __syncthreads();

  f32x4 acc[2];
  acc[0] = (f32x4){0.f,0.f,0.f,0.f};
  acc[1] = (f32x4){0.f,0.f,0.f,0.f};
  #pragma unroll
  for (int ks=0; ks<8; ks++){
    int row = w*16 + lm;
    bf16x8 af = *(const bf16x8*)(smY + row*512 + ((((ks*4+lk)*16)) ^ ((row&7)<<4)));
    #pragma unroll
    for (int nf=0; nf<2; nf++){
      int col = nf*16 + lm;
      bf16x8 bfr = *(const bf16x8*)(smLW + col*512 + (((ks*64 + lk*16)) ^ ((col&7)<<4)));
      acc[nf] = __builtin_amdgcn_mfma_f32_16x16x32_bf16(af, bfr, acc[nf], 0, 0, 0);
    }
  }

  int len = mel[b];
  float psum = 0.f; int pcol = -1;
  #pragma unroll
  for (int nf=0; nf<2; nf++){
    int o = nf*16 + lm;
    float lbv = (o < 22) ? lb[o] : 0.f;
    #pragma unroll
    for (int j=0; j<4; j++){
      int row = w*16 + lk*4 + j;
      int t = tbase + row;
      float v = acc[nf][j] + lbv;
      if (o < 20)      pspec[((size_t)b*Tn + t)*20 + o] = (t<len) ? v : 0.f;
      else if (o < 22){ psum += v; pcol = o - 20; }   // unmasked mean input
    }
  }
  if (pcol >= 0) pp[w][lk][pcol] = psum;   // written exactly for lm==4 (col0), lm==5 (col1)
  __syncthreads();
  if (tid < 2){
    float s = 0.f;
    #pragma unroll
    for (int a=0;a<4;a++)
      #pragma unroll
      for (int q=0;q<4;q++) s += pp[a][q][tid];
    atomicAdd(&ppar[2*b + tid], s * (1.f/Tn));
  }
}

// ---------------- quantize + embedding gather ----------------
__global__ void k_embed(const float* __restrict__ target, const float* __restrict__ alpha,
                        const int* __restrict__ mel, const float* __restrict__ emb,
                        float* __restrict__ out){
  int row  = blockIdx.x*4 + (threadIdx.x>>6);
  int lane = threadIdx.x & 63;
  int b = row >> 11, t = row & (Tn-1);
  int qid = 0;
  if (t < mel[b]){
    float q = target[row]*alpha[b];
    q = fminf(fmaxf(q, 0.f), 800.f);
    qid = (int)rintf(q/3.125f) + 1;
  }
  float4 v = ((const float4*)(emb + (size_t)qid*256))[lane];
  ((float4*)(out + (size_t)row*256))[lane] = v;
}

extern "C" void kernel_launch(void* const* d_in, const int* in_sizes, int n_in,
                              void* d_out, int out_size, void* d_ws, size_t ws_size,
                              hipStream_t stream) {
  const float* x      = (const float*)d_in[0];
  const float* alpha  = (const float*)d_in[1];
  const float* target = (const float*)d_in[2];
  const int*   mel    = (const int*)  d_in[3];
  const float* w1     = (const float*)d_in[4];
  const float* b1     = (const float*)d_in[5];
  const float* g1     = (const float*)d_in[6];
  const float* be1    = (const float*)d_in[7];
  const float* w2     = (const float*)d_in[8];
  const float* b2     = (const float*)d_in[9];
  const float* g2     = (const float*)d_in[10];
  const float* be2    = (const float*)d_in[11];
  const float* lw     = (const float*)d_in[12];
  const float* lb     = (const float*)d_in[13];
  const float* emb    = (const float*)d_in[14];
  float* out = (float*)d_out;
  char*  wsb = (char*)d_ws;

  char*   wb1 = wsb + OB_WB1;
  char*   wb2 = wsb + OB_WB2;
  char*   lwB = wsb + OB_LWB;
  __bf16* h1  = (__bf16*)(wsb + OB_H1);
  float*  X   = (float*)(wsb + OB_X);
  float*  Y1  = (float*)(wsb + OB_Y1);
  __bf16* Y   = (__bf16*)(wsb + OB_Y);

  k_fwd_dft<<<Bn*64, 256, 0, stream>>>(target, mel, X, out + O_TPAR, out + O_PPAR);
  k_idft1<<<dim3(32, Bn), 256, 0, stream>>>(X, Y1);
  k_idft2<<<dim3(64, Bn), 256, 0, stream>>>(Y1, mel, out + O_TSPEC);
  k_prep_w<<<1568, 256, 0, stream>>>(w1, w2, lw, wb1, wb2, lwB);
  k_conv_gemm<1><<<dim3(8, 4, Bn), 256, 0, stream>>>(x, wb1, b1, Y);
  k_ln1<<<Bn*Tn/16, 256, 0, stream>>>(Y, g1, be1, h1);
  k_conv_gemm<2><<<dim3(8, 4, Bn), 256, 0, stream>>>(h1, wb2, b2, Y);
  k_ln2lin<<<dim3(Tn/64, Bn), 256, 0, stream>>>(Y, g2, be2, lwB, lb, mel,
                                                out + O_PSPEC, out + O_PPAR);
  k_embed<<<Bn*Tn/4, 256, 0, stream>>>(target, alpha, mel, emb, out + O_EMB);
}